// Round 1
// baseline (672.381 us; speedup 1.0000x reference)
//
#include <hip/hip_runtime.h>
#include <math.h>

#define B_   8
#define C_   128
#define T_   64
#define N_   256
#define DIN  128
#define J2   256

// LDS strides (floats)
#define HT_S   68    // K-major H (and Y) — 16B-aligned rows, 2-way banks on b128
#define XC_S   66    // b32-only buffers — 2-way banks
#define Z_S    66
#define Y_S    68
#define WINT_S 260
#define WOUT_S 132
#define XD_S   17

// LDS float offsets
#define OFF_HT 0          // 128*68 = 8704 floats (in_proj A; reused as Y)
#define OFF_R2 8704       // 16*260 = 4160 floats (WinT -> XD -> WoutT)
#define OFF_XC 12864      // 128*66 = 8448
#define OFF_Z  21312      // 8448
#define OFF_WX 29760      // 16*128 = 2048
#define LDS_FLOATS 31808  // 127232 bytes

// ---------------- K1: LayerNorm over C + transpose to (B*N, T, C) ----------
__global__ __launch_bounds__(256) void k_ln(const float* __restrict__ x,
                                            const float* __restrict__ gam,
                                            const float* __restrict__ bet,
                                            float* __restrict__ hout) {
  __shared__ float tile[128 * 36];
  __shared__ float ps[8 * 32], pq[8 * 32], mean_s[32], rstd_s[32];
  int bx = blockIdx.x;
  int nt = bx & 7, t = (bx >> 3) & 63, b = bx >> 9;
  int n0 = nt * 32;
  int tid = threadIdx.x;
  const float4* x4 = (const float4*)x;
  // load 128c x 32n tile, coalesced along n
  for (int it = 0; it < 4; ++it) {
    int idx4 = it * 256 + tid;
    int c = idx4 >> 3, nn4 = idx4 & 7;
    float4 v = x4[((b * C_ + c) * T_ + t) * (N_ / 4) + (n0 >> 2) + nn4];
    *(float4*)&tile[c * 36 + nn4 * 4] = v;
  }
  __syncthreads();
  // reduce over c per n
  {
    int nn = tid & 31, cg = tid >> 5;
    float s = 0.f, q = 0.f;
    for (int i = 0; i < 16; ++i) {
      float v = tile[(cg * 16 + i) * 36 + nn];
      s += v; q += v * v;
    }
    ps[cg * 32 + nn] = s; pq[cg * 32 + nn] = q;
  }
  __syncthreads();
  if (tid < 32) {
    float ss = 0.f, qq = 0.f;
    for (int g2 = 0; g2 < 8; ++g2) { ss += ps[g2 * 32 + tid]; qq += pq[g2 * 32 + tid]; }
    float mu = ss * (1.f / 128.f);
    float var = qq * (1.f / 128.f) - mu * mu;
    mean_s[tid] = mu;
    rstd_s[tid] = rsqrtf(var + 1e-5f);
  }
  __syncthreads();
  // write (b*N+n, t, c) coalesced along c
  {
    int c = tid & 127, half = tid >> 7;
    float gm = gam[c], bb = bet[c];
    for (int it = 0; it < 16; ++it) {
      int n = it * 2 + half;
      float v = (tile[c * 36 + n] - mean_s[n]) * rstd_s[n] * gm + bb;
      hout[((b * N_ + n0 + n) * (long)T_ + t) * C_ + c] = v;
    }
  }
}

// ---------------- K2: fused per-sequence Mamba ------------------------------
__global__ __launch_bounds__(512) void k_mamba(
    const float* __restrict__ ws_h,   // (B*N, T, C) -- read then overwritten in place
    float* __restrict__ ws_y,
    const float* __restrict__ Win,    // (256,128)
    const float* __restrict__ convw,  // (3,1,128)
    const float* __restrict__ convb,  // (128)
    const float* __restrict__ Wx,     // (16,128)
    const float* __restrict__ Wdt,    // (128,8)
    const float* __restrict__ bdt,    // (128)
    const float* __restrict__ Alog,   // (128,4)
    const float* __restrict__ Dp,     // (128)
    const float* __restrict__ Wout)   // (128,128)
{
  extern __shared__ float L[];
  int bn = blockIdx.x;
  int tid = threadIdx.x;
  const float* hseq = ws_h + (long)bn * (T_ * C_);

  // stage Wx (16x128) row-major
  {
    const float4* w4 = (const float4*)Wx;
    *(float4*)&L[OFF_WX + tid * 4] = w4[tid];
  }
  // stage HT[c][t] (K-major H)
  {
    const float4* h4 = (const float4*)hseq;
    for (int it = 0; it < 4; ++it) {
      int idx4 = it * 512 + tid;
      int t = idx4 >> 5, c4 = idx4 & 31;
      float4 v = h4[idx4];
      L[OFF_HT + (c4 * 4 + 0) * HT_S + t] = v.x;
      L[OFF_HT + (c4 * 4 + 1) * HT_S + t] = v.y;
      L[OFF_HT + (c4 * 4 + 2) * HT_S + t] = v.z;
      L[OFF_HT + (c4 * 4 + 3) * HT_S + t] = v.w;
    }
  }
  __syncthreads();

  // ---- in_proj: xz(64x256) = H(64x128) @ Win^T, register-tiled ----
  int tm = tid & 15, tn = tid >> 4;   // t = tm*4..+4, j = tn*8..+8
  float acc[4][8];
#pragma unroll
  for (int i = 0; i < 4; ++i)
#pragma unroll
    for (int j = 0; j < 8; ++j) acc[i][j] = 0.f;
  const float4* Win4 = (const float4*)Win;
  for (int kb = 0; kb < 8; ++kb) {
    // stage WinT[kk][j] chunk (16 x 256)
    for (int it = 0; it < 2; ++it) {
      int idx4 = it * 512 + tid;
      int j = idx4 >> 2, w = idx4 & 3;
      float4 v = Win4[j * 32 + kb * 4 + w];
      L[OFF_R2 + (w * 4 + 0) * WINT_S + j] = v.x;
      L[OFF_R2 + (w * 4 + 1) * WINT_S + j] = v.y;
      L[OFF_R2 + (w * 4 + 2) * WINT_S + j] = v.z;
      L[OFF_R2 + (w * 4 + 3) * WINT_S + j] = v.w;
    }
    __syncthreads();
#pragma unroll
    for (int kk = 0; kk < 16; ++kk) {
      int k = kb * 16 + kk;
      float4 a  = *(const float4*)&L[OFF_HT + k * HT_S + tm * 4];
      float4 b0 = *(const float4*)&L[OFF_R2 + kk * WINT_S + tn * 8];
      float4 b1 = *(const float4*)&L[OFF_R2 + kk * WINT_S + tn * 8 + 4];
      float av[4] = {a.x, a.y, a.z, a.w};
      float bv[8] = {b0.x, b0.y, b0.z, b0.w, b1.x, b1.y, b1.z, b1.w};
#pragma unroll
      for (int i = 0; i < 4; ++i)
#pragma unroll
        for (int j = 0; j < 8; ++j)
          acc[i][j] = fmaf(av[i], bv[j], acc[i][j]);
    }
    __syncthreads();
  }
  // scatter xz -> XC (j<128) / Z (j>=128), [d][t] layout
  {
#pragma unroll
    for (int i = 0; i < 4; ++i) {
      int t = tm * 4 + i;
#pragma unroll
      for (int j = 0; j < 8; ++j) {
        int jj = tn * 8 + j;
        if (jj < 128) L[OFF_XC + jj * XC_S + t] = acc[i][j];
        else          L[OFF_Z + (jj - 128) * Z_S + t] = acc[i][j];
      }
    }
  }
  __syncthreads();

  // ---- causal depthwise conv(3) + SiLU, in place on XC ----
  {
    int d = tid & 127, tq = tid >> 7;
    int t0 = tq * 16;
    float w0 = convw[d], w1 = convw[128 + d], w2 = convw[256 + d], cb = convb[d];
    float xin[18];
#pragma unroll
    for (int i = 0; i < 18; ++i) {
      int t = t0 - 2 + i;
      xin[i] = (t < 0) ? 0.f : L[OFF_XC + d * XC_S + t];
    }
    __syncthreads();   // all pre-conv reads done before overwrite
#pragma unroll
    for (int i = 0; i < 16; ++i) {
      float v = fmaf(w2, xin[i + 2], fmaf(w1, xin[i + 1], fmaf(w0, xin[i], cb)));
      float sv = v / (1.f + expf(-v));   // silu
      L[OFF_XC + d * XC_S + t0 + i] = sv;
    }
  }
  __syncthreads();

  // ---- x_proj: x_dbl(64x16) = XC^T @ Wx^T ----
  {
    int t = tid & 63, rg = tid >> 6;   // rg 0..7, r = rg*2 + {0,1}
    float a0 = 0.f, a1 = 0.f;
    const float* wx0 = &L[OFF_WX + (rg * 2 + 0) * 128];
    const float* wx1 = &L[OFF_WX + (rg * 2 + 1) * 128];
#pragma unroll 8
    for (int d = 0; d < 128; ++d) {
      float xv = L[OFF_XC + d * XC_S + t];
      a0 = fmaf(xv, wx0[d], a0);
      a1 = fmaf(xv, wx1[d], a1);
    }
    L[OFF_R2 + t * XD_S + rg * 2 + 0] = a0;
    L[OFF_R2 + t * XD_S + rg * 2 + 1] = a1;
  }
  __syncthreads();

  // ---- dt_proj + softplus + selective scan + gate (threads = channel d) ----
  if (tid < 128) {
    int d = tid;
    float4 wd0 = *(const float4*)&Wdt[d * 8];
    float4 wd1 = *(const float4*)&Wdt[d * 8 + 4];
    float bd = bdt[d];
    float4 al = *(const float4*)&Alog[d * 4];
    float A0 = -expf(al.x), A1 = -expf(al.y), A2 = -expf(al.z), A3 = -expf(al.w);
    float Dd = Dp[d];
    float h0 = 0.f, h1 = 0.f, h2 = 0.f, h3 = 0.f;
    for (int t = 0; t < 64; ++t) {
      const float* xd = &L[OFF_R2 + t * XD_S];
      float dtr = bd;
      dtr = fmaf(xd[0], wd0.x, dtr); dtr = fmaf(xd[1], wd0.y, dtr);
      dtr = fmaf(xd[2], wd0.z, dtr); dtr = fmaf(xd[3], wd0.w, dtr);
      dtr = fmaf(xd[4], wd1.x, dtr); dtr = fmaf(xd[5], wd1.y, dtr);
      dtr = fmaf(xd[6], wd1.z, dtr); dtr = fmaf(xd[7], wd1.w, dtr);
      float dt = (dtr > 20.f) ? dtr : log1pf(expf(dtr));  // softplus
      float Bv0 = xd[8],  Bv1 = xd[9],  Bv2 = xd[10], Bv3 = xd[11];
      float Cv0 = xd[12], Cv1 = xd[13], Cv2 = xd[14], Cv3 = xd[15];
      float xcv = L[OFF_XC + d * XC_S + t];
      float dbx = dt * xcv;
      h0 = fmaf(h0, expf(dt * A0), dbx * Bv0);
      h1 = fmaf(h1, expf(dt * A1), dbx * Bv1);
      h2 = fmaf(h2, expf(dt * A2), dbx * Bv2);
      h3 = fmaf(h3, expf(dt * A3), dbx * Bv3);
      float y = fmaf(h0, Cv0, fmaf(h1, Cv1, fmaf(h2, Cv2, h3 * Cv3)));
      y = fmaf(xcv, Dd, y);
      float zv = L[OFF_Z + d * Z_S + t];
      y *= zv / (1.f + expf(-zv));       // * silu(z)
      L[OFF_HT + d * Y_S + t] = y;       // Y reuses HT region, [d][t]
    }
  }
  __syncthreads();

  // ---- out_proj: out(64x128) = Y^T @ Wout^T, register-tiled ----
  {
    float oacc[4][4];
#pragma unroll
    for (int i = 0; i < 4; ++i)
#pragma unroll
      for (int j = 0; j < 4; ++j) oacc[i][j] = 0.f;
    const float4* Wout4 = (const float4*)Wout;
    for (int kb = 0; kb < 8; ++kb) {
      {  // stage WoutT[kk][c] chunk (16 x 128)
        int c = tid & 127, k4 = tid >> 7;
        float4 v = Wout4[c * 32 + kb * 4 + k4];
        L[OFF_R2 + (k4 * 4 + 0) * WOUT_S + c] = v.x;
        L[OFF_R2 + (k4 * 4 + 1) * WOUT_S + c] = v.y;
        L[OFF_R2 + (k4 * 4 + 2) * WOUT_S + c] = v.z;
        L[OFF_R2 + (k4 * 4 + 3) * WOUT_S + c] = v.w;
      }
      __syncthreads();
#pragma unroll
      for (int kk = 0; kk < 16; ++kk) {
        int k = kb * 16 + kk;
        float4 a = *(const float4*)&L[OFF_HT + k * Y_S + tm * 4];
        float4 b = *(const float4*)&L[OFF_R2 + kk * WOUT_S + tn * 4];
        float av[4] = {a.x, a.y, a.z, a.w};
        float bv[4] = {b.x, b.y, b.z, b.w};
#pragma unroll
        for (int i = 0; i < 4; ++i)
#pragma unroll
          for (int j = 0; j < 4; ++j)
            oacc[i][j] = fmaf(av[i], bv[j], oacc[i][j]);
      }
      __syncthreads();
    }
    // write (bn, t, c) in place over ws
    float* yout = ws_y + (long)bn * (T_ * C_);
#pragma unroll
    for (int i = 0; i < 4; ++i) {
      int t = tm * 4 + i;
      float4 v;
      v.x = oacc[i][0]; v.y = oacc[i][1]; v.z = oacc[i][2]; v.w = oacc[i][3];
      *(float4*)&yout[t * C_ + tn * 4] = v;
    }
  }
}

// ---------------- K3: transpose (B*N,T,C) -> (B,C,T,N) ----------------------
__global__ __launch_bounds__(256) void k_out_tr(const float* __restrict__ ws_y,
                                                float* __restrict__ out) {
  __shared__ float tile[32 * 132];
  int bx = blockIdx.x;
  int nt = bx & 7, t = (bx >> 3) & 63, b = bx >> 9;
  int n0 = nt * 32;
  int tid = threadIdx.x;
  const float4* y4 = (const float4*)ws_y;
  for (int it = 0; it < 4; ++it) {
    int idx4 = it * 256 + tid;
    int nn = idx4 >> 5, c4 = idx4 & 31;
    float4 v = y4[((b * N_ + n0 + nn) * (long)T_ + t) * (C_ / 4) + c4];
    *(float4*)&tile[nn * 132 + c4 * 4] = v;
  }
  __syncthreads();
  int nn = tid & 31, cg = tid >> 5;
  for (int i = 0; i < 16; ++i) {
    int c = cg * 16 + i;
    out[((b * C_ + c) * (long)T_ + t) * N_ + n0 + nn] = tile[nn * 132 + c];
  }
}

extern "C" void kernel_launch(void* const* d_in, const int* in_sizes, int n_in,
                              void* d_out, int out_size, void* d_ws, size_t ws_size,
                              hipStream_t stream) {
  const float* x    = (const float*)d_in[0];
  const float* gam  = (const float*)d_in[1];
  const float* bet  = (const float*)d_in[2];
  const float* Win  = (const float*)d_in[3];
  const float* cw   = (const float*)d_in[4];
  const float* cb   = (const float*)d_in[5];
  const float* Wx   = (const float*)d_in[6];
  const float* Wdt  = (const float*)d_in[7];
  const float* bdt  = (const float*)d_in[8];
  const float* Alog = (const float*)d_in[9];
  const float* Dp   = (const float*)d_in[10];
  const float* Wout = (const float*)d_in[11];
  float* out = (float*)d_out;
  float* ws  = (float*)d_ws;   // uses 64 MB: (B*N, T, C) fp32

  (void)hipFuncSetAttribute((const void*)k_mamba,
                            hipFuncAttributeMaxDynamicSharedMemorySize,
                            LDS_FLOATS * 4);

  k_ln<<<4096, 256, 0, stream>>>(x, gam, bet, ws);
  k_mamba<<<2048, 512, LDS_FLOATS * 4, stream>>>(ws, ws, Win, cw, cb, Wx, Wdt,
                                                 bdt, Alog, Dp, Wout);
  k_out_tr<<<4096, 256, 0, stream>>>(ws, out);
}